// Round 7
// baseline (934.777 us; speedup 1.0000x reference)
//
#include <hip/hip_runtime.h>
#include <hip/hip_bf16.h>

#define NN 100000
#define NE 1600000
#define HIDD 128
#define NB_X 1563   // ceil(NN / 64)
#define NSB 98      // ceil(NN / 1024) scan blocks
#define NBUK 782    // ceil(NN / 128) dst-buckets for radix fill
#define LDAS 136    // A-tile LDS row stride in bf16 (272 B -> 2-way conflict, free)

typedef short short8 __attribute__((ext_vector_type(8)));
typedef float f32x4 __attribute__((ext_vector_type(4)));

__device__ inline short f2bf(float f) {
    union { float f; unsigned int u; } v; v.f = f;
    unsigned int u = v.u + 0x7FFF + ((v.u >> 16) & 1);   // RNE
    return (short)(u >> 16);
}

// ---------------------------------------------------------------------------
// Convert X f32 -> packed bf16 pairs (uint per 2 features)
__global__ __launch_bounds__(256) void convert_x_kernel(
    const float* __restrict__ X, unsigned int* __restrict__ Xb)
{
    int i = blockIdx.x * 256 + threadIdx.x;          // < NN*64
    const float2 v = *(const float2*)(X + (size_t)i * 2);
    unsigned int lo = (unsigned short)f2bf(v.x);
    unsigned int hi = (unsigned short)f2bf(v.y);
    Xb[i] = lo | (hi << 16);
}

// ---------------------------------------------------------------------------
// CSR build step 1: degree count
__global__ __launch_bounds__(256) void count_kernel(
    const int* __restrict__ dst, int* __restrict__ degcur)
{
    int e = blockIdx.x * 256 + threadIdx.x;
    atomicAdd(&degcur[dst[e]], 1);
}

// ---------------------------------------------------------------------------
// Scan phase 1: per-block (1024 elems) scan via wave shfl + LDS
__global__ __launch_bounds__(1024) void scan1_kernel(
    const int* __restrict__ deg, int* __restrict__ scanned,
    int* __restrict__ bsum)
{
    const int t    = threadIdx.x;
    const int i    = blockIdx.x * 1024 + t;
    const int lane = t & 63;
    const int w    = t >> 6;

    int v = (i < NN) ? deg[i] : 0;
    int x = v;
    #pragma unroll
    for (int off = 1; off < 64; off <<= 1) {
        int y = __shfl_up(x, off);
        if (lane >= off) x += y;
    }
    __shared__ int wsum[16];
    if (lane == 63) wsum[w] = x;
    __syncthreads();
    if (w == 0) {
        int s = (lane < 16) ? wsum[lane] : 0;
        #pragma unroll
        for (int off = 1; off < 16; off <<= 1) {
            int y = __shfl_up(s, off);
            if (lane >= off) s += y;
        }
        if (lane < 16) wsum[lane] = s;
    }
    __syncthreads();
    int base = (w > 0) ? wsum[w - 1] : 0;
    int incl = base + x;
    scanned[i] = incl - v;
    if (t == 1023) bsum[blockIdx.x] = incl;
}

// ---------------------------------------------------------------------------
__global__ __launch_bounds__(128) void scan2_kernel(
    const int* __restrict__ bsum, int* __restrict__ bbase,
    int* __restrict__ offs)
{
    __shared__ int sh[128];
    const int t = threadIdx.x;
    int v = (t < NSB) ? bsum[t] : 0;
    sh[t] = v;
    __syncthreads();
    for (int off = 1; off < 128; off <<= 1) {
        int add = (t >= off) ? sh[t - off] : 0;
        __syncthreads();
        sh[t] += add;
        __syncthreads();
    }
    if (t < NSB) bbase[t] = sh[t] - v;
    if (t == NSB - 1) offs[NN] = sh[t];
}

// ---------------------------------------------------------------------------
__global__ __launch_bounds__(1024) void scan3_kernel(
    const int* __restrict__ scanned, const int* __restrict__ bbase,
    int* __restrict__ offs)
{
    int i = blockIdx.x * 1024 + threadIdx.x;
    if (i < NN) offs[i] = scanned[i] + bbase[blockIdx.x];
}

// ---------------------------------------------------------------------------
// Radix fill A: bucket cursors = offs at bucket boundaries
__global__ __launch_bounds__(1024) void init_bcur_kernel(
    const int* __restrict__ offs, int* __restrict__ bcur)
{
    int b = threadIdx.x;
    if (b < NBUK) bcur[b] = offs[b * 128];
}

// ---------------------------------------------------------------------------
// Radix fill B: scatter packed (src | dstLocal<<17) into bucket regions (4B)
__global__ __launch_bounds__(256) void partB_kernel(
    const int* __restrict__ src, const int* __restrict__ dst,
    int* __restrict__ bcur, int* __restrict__ pairs)
{
    int e = blockIdx.x * 256 + threadIdx.x;
    int d = dst[e];
    int pos = atomicAdd(&bcur[d >> 7], 1);
    pairs[pos] = src[e] | ((d & 127) << 17);
}

// ---------------------------------------------------------------------------
// Radix fill C: per-bucket finalize via LDS node-cursors; dense esrc writes
__global__ __launch_bounds__(256) void partC_kernel(
    const int* __restrict__ offs, const int* __restrict__ pairs,
    int* __restrict__ esrc)
{
    __shared__ int lcur[128];
    const int b = blockIdx.x;
    const int t = threadIdx.x;
    const int n0 = b * 128;
    if (t < 128) {
        int n = n0 + t;
        lcur[t] = (n < NN) ? offs[n] : 0;
    }
    __syncthreads();
    const int start = offs[n0];
    const int end   = offs[min(n0 + 128, NN)];
    for (int i = start + t; i < end; i += 256) {
        int p  = pairs[i];
        int s  = p & 0x1FFFF;
        int dl = ((unsigned int)p) >> 17;
        int pos = atomicAdd(&lcur[dl], 1);
        esrc[pos] = s;
    }
}

// ---------------------------------------------------------------------------
// Convert 4 weight matrices f32[k][n] -> bf16 transposed wt[n][k]
__global__ __launch_bounds__(256) void convert_w_kernel(
    const float* __restrict__ w0, const float* __restrict__ w1,
    const float* __restrict__ w2, const float* __restrict__ w3,
    short* __restrict__ wt)
{
    const float* wsrc = (blockIdx.x == 0) ? w0 : (blockIdx.x == 1) ? w1
                      : (blockIdx.x == 2) ? w2 : w3;
    short* o = wt + blockIdx.x * 16384;
    for (int p = 0; p < 64; ++p) {
        int idx = p * 256 + threadIdx.x;
        int n = idx >> 7, k = idx & 127;
        o[n * 128 + k] = f2bf(wsrc[k * 128 + n]);
    }
}

// ---------------------------------------------------------------------------
// Gather + combine (bf16 in, bf16 out):
// A[n] = bf16((1+eps)*X[n] + sum X[src(e)]), X packed 2xbf16/uint
__global__ __launch_bounds__(256) void gather_kernel(
    const unsigned int* __restrict__ Xb, const int* __restrict__ offs,
    const int* __restrict__ esrc, const float* __restrict__ epsp,
    unsigned int* __restrict__ Ab)
{
    const int gid  = blockIdx.x * 256 + threadIdx.x;
    const int n    = gid >> 6;
    const int lane = threadIdx.x & 63;
    if (n >= NN) return;

    const int beg = offs[n], end = offs[n + 1];
    const float ep = 1.0f + epsp[0];

    float s0x = 0.f, s0y = 0.f, s1x = 0.f, s1y = 0.f;
    float s2x = 0.f, s2y = 0.f, s3x = 0.f, s3y = 0.f;
    union { unsigned int u; float f; } c;
    int i = beg;
    for (; i + 3 < end; i += 4) {
        unsigned int v0 = Xb[(size_t)esrc[i]     * 64 + lane];
        unsigned int v1 = Xb[(size_t)esrc[i + 1] * 64 + lane];
        unsigned int v2 = Xb[(size_t)esrc[i + 2] * 64 + lane];
        unsigned int v3 = Xb[(size_t)esrc[i + 3] * 64 + lane];
        c.u = v0 << 16;          s0x += c.f;
        c.u = v0 & 0xFFFF0000u;  s0y += c.f;
        c.u = v1 << 16;          s1x += c.f;
        c.u = v1 & 0xFFFF0000u;  s1y += c.f;
        c.u = v2 << 16;          s2x += c.f;
        c.u = v2 & 0xFFFF0000u;  s2y += c.f;
        c.u = v3 << 16;          s3x += c.f;
        c.u = v3 & 0xFFFF0000u;  s3y += c.f;
    }
    for (; i < end; ++i) {
        unsigned int v = Xb[(size_t)esrc[i] * 64 + lane];
        c.u = v << 16;           s0x += c.f;
        c.u = v & 0xFFFF0000u;   s0y += c.f;
    }
    unsigned int xv = Xb[(size_t)n * 64 + lane];
    float xl, xh;
    c.u = xv << 16;          xl = c.f;
    c.u = xv & 0xFFFF0000u;  xh = c.f;
    float ox = fmaf(ep, xl, (s0x + s1x) + (s2x + s3x));
    float oy = fmaf(ep, xh, (s0y + s1y) + (s2y + s3y));
    unsigned int lo = (unsigned short)f2bf(ox);
    unsigned int hi = (unsigned short)f2bf(oy);
    Ab[(size_t)n * 64 + lane] = lo | (hi << 16);
}

// ---------------------------------------------------------------------------
// MFMA GEMM1: Hb = bf16( Ab @ Wt^T + bias ), BN partials per block.
__global__ __launch_bounds__(256) void gemm_stats_mfma(
    const short* __restrict__ Ab, const short* __restrict__ Wt,
    const float* __restrict__ bias, short* __restrict__ Hb,
    float* __restrict__ partial)
{
    __shared__ short As[64 * LDAS];
    __shared__ float sred[256];
    const int tid  = threadIdx.x;
    const int row0 = blockIdx.x * 64;

    #pragma unroll
    for (int p = 0; p < 4; ++p) {
        int c  = p * 256 + tid;
        int r  = c >> 4, k8 = c & 15;
        int row = row0 + r;
        short8 v = {};
        if (row < NN) v = *(const short8*)(Ab + (size_t)row * 128 + k8 * 8);
        *(short8*)(&As[r * LDAS + k8 * 8]) = v;
    }
    sred[tid] = 0.f;
    __syncthreads();

    const int w  = tid >> 6;
    const int l  = tid & 63;
    const int cl = l & 15;
    const int koff = (l >> 4) * 8;
    const int arow = w * 16 + cl;

    short8 afr[4];
    #pragma unroll
    for (int kb = 0; kb < 4; ++kb)
        afr[kb] = *(const short8*)(&As[arow * LDAS + kb * 32 + koff]);

    #pragma unroll
    for (int n = 0; n < 8; ++n) {
        f32x4 acc = {0.f, 0.f, 0.f, 0.f};
        const short* wp = Wt + (size_t)(n * 16 + cl) * 128 + koff;
        #pragma unroll
        for (int kb = 0; kb < 4; ++kb) {
            short8 bfr = *(const short8*)(wp + kb * 32);
            acc = __builtin_amdgcn_mfma_f32_16x16x32_bf16(afr[kb], bfr, acc, 0, 0, 0);
        }
        const int col = n * 16 + cl;
        const float bcol = bias[col];
        float ps = 0.f, pq = 0.f;
        #pragma unroll
        for (int i = 0; i < 4; ++i) {
            int row = row0 + w * 16 + ((l >> 4) << 2) + i;
            if (row < NN) {
                float h = acc[i] + bcol;
                Hb[(size_t)row * 128 + col] = f2bf(h);
                ps += h; pq += h * h;
            }
        }
        ps += __shfl_xor(ps, 16); pq += __shfl_xor(pq, 16);
        ps += __shfl_xor(ps, 32); pq += __shfl_xor(pq, 32);
        if (l < 16) {
            atomicAdd(&sred[col], ps);
            atomicAdd(&sred[128 + col], pq);
        }
    }
    __syncthreads();
    partial[(size_t)blockIdx.x * 256 + tid] = sred[tid];
}

// ---------------------------------------------------------------------------
__global__ __launch_bounds__(1024) void reduce_stats_kernel(
    const float* __restrict__ partial, const float* __restrict__ g,
    const float* __restrict__ bt, float* __restrict__ stats)
{
    __shared__ float buf[4][256];
    const int t  = threadIdx.x;
    const int c  = t & 255;
    const int ch = t >> 8;
    const int per = (NB_X + 3) / 4;
    const int b0 = ch * per;
    const int b1 = min(b0 + per, NB_X);

    float s = 0.f;
    #pragma unroll 8
    for (int b = b0; b < b1; ++b) s += partial[(size_t)b * 256 + c];
    buf[ch][c] = s;
    __syncthreads();

    if (t < 256) buf[0][t] = buf[0][t] + buf[1][t] + buf[2][t] + buf[3][t];
    __syncthreads();

    if (t < 128) {
        const float invN = 1.0f / (float)NN;
        float mu  = buf[0][t] * invN;
        float var = buf[0][128 + t] * invN - mu * mu;
        float sc  = g[t] * rsqrtf(var + 1e-5f);
        stats[256 + t] = sc;
        stats[384 + t] = bt[t] - mu * sc;
    }
}

// ---------------------------------------------------------------------------
// MFMA GEMM2: T = relu(bn(Hb)) @ Wt^T + bias.
// mode=1: write relu(T) as packed bf16 to Yb (layer-1 intermediate).
// mode=0: write T as f32 to Yf (final output).
__global__ __launch_bounds__(256) void gemm_post_mfma(
    const short* __restrict__ Hb, const float* __restrict__ stats,
    const short* __restrict__ Wt, const float* __restrict__ bias,
    short* __restrict__ Yb, float* __restrict__ Yf, int mode)
{
    __shared__ short As[64 * LDAS];
    const int tid  = threadIdx.x;
    const int row0 = blockIdx.x * 64;

    #pragma unroll
    for (int p = 0; p < 4; ++p) {
        int c  = p * 256 + tid;
        int r  = c >> 4, k8 = c & 15;
        int row = row0 + r;
        short8 v = {};
        if (row < NN) {
            short8 hv = *(const short8*)(Hb + (size_t)row * 128 + k8 * 8);
            #pragma unroll
            for (int j = 0; j < 8; ++j) {
                int k = k8 * 8 + j;
                union { unsigned int u; float f; } cv;
                cv.u = ((unsigned int)(unsigned short)hv[j]) << 16;
                float f = fmaxf(fmaf(cv.f, stats[256 + k], stats[384 + k]), 0.f);
                v[j] = f2bf(f);
            }
        }
        *(short8*)(&As[r * LDAS + k8 * 8]) = v;
    }
    __syncthreads();

    const int w  = tid >> 6;
    const int l  = tid & 63;
    const int cl = l & 15;
    const int koff = (l >> 4) * 8;
    const int arow = w * 16 + cl;

    short8 afr[4];
    #pragma unroll
    for (int kb = 0; kb < 4; ++kb)
        afr[kb] = *(const short8*)(&As[arow * LDAS + kb * 32 + koff]);

    #pragma unroll
    for (int n = 0; n < 8; ++n) {
        f32x4 acc = {0.f, 0.f, 0.f, 0.f};
        const short* wp = Wt + (size_t)(n * 16 + cl) * 128 + koff;
        #pragma unroll
        for (int kb = 0; kb < 4; ++kb) {
            short8 bfr = *(const short8*)(wp + kb * 32);
            acc = __builtin_amdgcn_mfma_f32_16x16x32_bf16(afr[kb], bfr, acc, 0, 0, 0);
        }
        const int col = n * 16 + cl;
        const float bcol = bias[col];
        #pragma unroll
        for (int i = 0; i < 4; ++i) {
            int row = row0 + w * 16 + ((l >> 4) << 2) + i;
            if (row < NN) {
                float h = acc[i] + bcol;
                if (mode == 1) {
                    h = fmaxf(h, 0.f);
                    Yb[(size_t)row * 128 + col] = f2bf(h);
                } else {
                    Yf[(size_t)row * 128 + col] = h;
                }
            }
        }
    }
}

// ---------------------------------------------------------------------------
extern "C" void kernel_launch(void* const* d_in, const int* in_sizes, int n_in,
                              void* d_out, int out_size, void* d_ws, size_t ws_size,
                              hipStream_t stream)
{
    const float* x    = (const float*)d_in[0];
    const int*   src  = (const int*)  d_in[1];
    const int*   dst  = (const int*)  d_in[2];
    const float* eps1 = (const float*)d_in[3];
    const float* w1a  = (const float*)d_in[4];
    const float* b1a  = (const float*)d_in[5];
    const float* g1   = (const float*)d_in[6];
    const float* bt1  = (const float*)d_in[7];
    const float* w1b  = (const float*)d_in[8];
    const float* b1b  = (const float*)d_in[9];
    const float* eps2 = (const float*)d_in[10];
    const float* w2a  = (const float*)d_in[11];
    const float* b2a  = (const float*)d_in[12];
    const float* g2   = (const float*)d_in[13];
    const float* bt2  = (const float*)d_in[14];
    const float* w2b  = (const float*)d_in[15];
    const float* b2b  = (const float*)d_in[16];

    float* out = (float*)d_out;

    // workspace layout (16B-aligned by construction)
    short*        Ab      = (short*)d_ws;                     // NN*128 bf16
    short*        Hb      = Ab + (size_t)NN * 128;            // NN*128 bf16
    unsigned int* Xcur    = (unsigned int*)(Hb + (size_t)NN * 128); // NN*64 uint
    float*        stats   = (float*)(Xcur + (size_t)NN * 64); // 512
    float*        partial = stats + 512;                      // NB_X*256
    int*          offs    = (int*)(partial + (size_t)NB_X * 256); // NN+4
    int*          degcur  = offs + (NN + 4);                  // NN
    int*          esrc    = degcur + NN;                      // NE
    int*          pairs   = esrc + NE;                        // NE
    int*          scanned = pairs + NE;                       // NSB*1024
    int*          bsum    = scanned + NSB * 1024;             // 100 (pad)
    int*          bbase   = bsum + 100;                       // 100 (pad)
    int*          bcur    = bbase + 100;                      // NBUK (pad 784)
    short*        wt      = (short*)(bcur + 784);             // 4*16384 bf16

    const int edge_blocks   = NE / 256;                  // 6250
    const int gather_blocks = (NN * 64 + 255) / 256;     // 25000
    const int convx_blocks  = NN * 64 / 256;             // 25000

    // ---- one-time prep ----
    convert_w_kernel<<<4, 256, 0, stream>>>(w1a, w1b, w2a, w2b, wt);
    convert_x_kernel<<<convx_blocks, 256, 0, stream>>>(x, Xcur);
    hipMemsetAsync(degcur, 0, NN * sizeof(int), stream);
    count_kernel<<<edge_blocks, 256, 0, stream>>>(dst, degcur);
    scan1_kernel<<<NSB, 1024, 0, stream>>>(degcur, scanned, bsum);
    scan2_kernel<<<1, 128, 0, stream>>>(bsum, bbase, offs);
    scan3_kernel<<<NSB, 1024, 0, stream>>>(scanned, bbase, offs);
    init_bcur_kernel<<<1, 1024, 0, stream>>>(offs, bcur);
    partB_kernel<<<edge_blocks, 256, 0, stream>>>(src, dst, bcur, pairs);
    partC_kernel<<<NBUK, 256, 0, stream>>>(offs, pairs, esrc);

    // ---- Layer 1 (input Xcur = bf16(x)) ----
    gather_kernel<<<gather_blocks, 256, 0, stream>>>(Xcur, offs, esrc, eps1,
                                                     (unsigned int*)Ab);
    gemm_stats_mfma<<<NB_X, 256, 0, stream>>>(Ab, wt, b1a, Hb, partial);
    reduce_stats_kernel<<<1, 1024, 0, stream>>>(partial, g1, bt1, stats);
    gemm_post_mfma<<<NB_X, 256, 0, stream>>>(Hb, stats, wt + 16384, b1b,
                                             (short*)Xcur, nullptr, 1);

    // ---- Layer 2 (input Xcur = bf16(relu(gin1))) ----
    gather_kernel<<<gather_blocks, 256, 0, stream>>>(Xcur, offs, esrc, eps2,
                                                     (unsigned int*)Ab);
    gemm_stats_mfma<<<NB_X, 256, 0, stream>>>(Ab, wt + 32768, b2a, Hb, partial);
    reduce_stats_kernel<<<1, 1024, 0, stream>>>(partial, g2, bt2, stats);
    gemm_post_mfma<<<NB_X, 256, 0, stream>>>(Hb, stats, wt + 49152, b2b,
                                             nullptr, out, 0);
}

// Round 8
// 620.304 us; speedup vs baseline: 1.5070x; 1.5070x over previous
//
#include <hip/hip_runtime.h>
#include <hip/hip_bf16.h>

#define NN 100000
#define NE 1600000
#define HIDD 128
#define NB_X 1563   // ceil(NN / 64)
#define NSB 98      // ceil(NN / 1024) scan blocks
#define SBUK 98     // super-buckets (1024 nodes each) for radix fill
#define EPB 4096    // edges per partB block
#define NBLK_B 391  // ceil(NE / EPB)
#define LDAS 136    // A-tile LDS row stride in bf16 (272 B -> 2-way, free)

typedef short short8 __attribute__((ext_vector_type(8)));
typedef float f32x4 __attribute__((ext_vector_type(4)));

__device__ inline short f2bf(float f) {
    union { float f; unsigned int u; } v; v.f = f;
    unsigned int u = v.u + 0x7FFF + ((v.u >> 16) & 1);   // RNE
    return (short)(u >> 16);
}

// ---------------------------------------------------------------------------
// Convert X f32 -> packed bf16 pairs (uint per 2 features)
__global__ __launch_bounds__(256) void convert_x_kernel(
    const float* __restrict__ X, unsigned int* __restrict__ Xb)
{
    int i = blockIdx.x * 256 + threadIdx.x;          // < NN*64
    const float2 v = *(const float2*)(X + (size_t)i * 2);
    unsigned int lo = (unsigned short)f2bf(v.x);
    unsigned int hi = (unsigned short)f2bf(v.y);
    Xb[i] = lo | (hi << 16);
}

// ---------------------------------------------------------------------------
__global__ __launch_bounds__(256) void count_kernel(
    const int* __restrict__ dst, int* __restrict__ degcur)
{
    int e = blockIdx.x * 256 + threadIdx.x;
    atomicAdd(&degcur[dst[e]], 1);
}

// ---------------------------------------------------------------------------
__global__ __launch_bounds__(1024) void scan1_kernel(
    const int* __restrict__ deg, int* __restrict__ scanned,
    int* __restrict__ bsum)
{
    const int t    = threadIdx.x;
    const int i    = blockIdx.x * 1024 + t;
    const int lane = t & 63;
    const int w    = t >> 6;

    int v = (i < NN) ? deg[i] : 0;
    int x = v;
    #pragma unroll
    for (int off = 1; off < 64; off <<= 1) {
        int y = __shfl_up(x, off);
        if (lane >= off) x += y;
    }
    __shared__ int wsum[16];
    if (lane == 63) wsum[w] = x;
    __syncthreads();
    if (w == 0) {
        int s = (lane < 16) ? wsum[lane] : 0;
        #pragma unroll
        for (int off = 1; off < 16; off <<= 1) {
            int y = __shfl_up(s, off);
            if (lane >= off) s += y;
        }
        if (lane < 16) wsum[lane] = s;
    }
    __syncthreads();
    int base = (w > 0) ? wsum[w - 1] : 0;
    int incl = base + x;
    scanned[i] = incl - v;
    if (t == 1023) bsum[blockIdx.x] = incl;
}

// ---------------------------------------------------------------------------
__global__ __launch_bounds__(128) void scan2_kernel(
    const int* __restrict__ bsum, int* __restrict__ bbase,
    int* __restrict__ offs)
{
    __shared__ int sh[128];
    const int t = threadIdx.x;
    int v = (t < NSB) ? bsum[t] : 0;
    sh[t] = v;
    __syncthreads();
    for (int off = 1; off < 128; off <<= 1) {
        int add = (t >= off) ? sh[t - off] : 0;
        __syncthreads();
        sh[t] += add;
        __syncthreads();
    }
    if (t < NSB) bbase[t] = sh[t] - v;
    if (t == NSB - 1) offs[NN] = sh[t];
}

// ---------------------------------------------------------------------------
__global__ __launch_bounds__(1024) void scan3_kernel(
    const int* __restrict__ scanned, const int* __restrict__ bbase,
    int* __restrict__ offs)
{
    int i = blockIdx.x * 1024 + threadIdx.x;
    if (i < NN) offs[i] = scanned[i] + bbase[blockIdx.x];
}

// ---------------------------------------------------------------------------
// bucket cursors = offs at 1024-node boundaries
__global__ __launch_bounds__(128) void init_bcur_kernel(
    const int* __restrict__ offs, int* __restrict__ bcur)
{
    int b = threadIdx.x;
    if (b < SBUK) bcur[b] = offs[b << 10];
}

// ---------------------------------------------------------------------------
// Radix fill B (staged, coalesced): per-block LDS histogram over 98 buckets,
// one run-reservation atomic per (block,bucket), LDS-ordered stage, then
// consecutive-address writeout of (src | dstLocal<<17) runs.
__global__ __launch_bounds__(256) void partB_kernel(
    const int* __restrict__ src, const int* __restrict__ dst,
    int* __restrict__ bcur, int* __restrict__ pairs)
{
    __shared__ int hist[SBUK];     // counts -> lds cursor
    __shared__ int lofs[SBUK];     // exclusive scan (lds layout)
    __shared__ int base[SBUK];     // global run base
    __shared__ int sc[128];
    __shared__ int stageVal[EPB];  // 16 KB
    __shared__ int stageGp[EPB];   // 16 KB
    const int t  = threadIdx.x;
    const int e0 = blockIdx.x * EPB;
    const int total = min(NE - e0, EPB);

    for (int i = t; i < SBUK; i += 256) hist[i] = 0;
    __syncthreads();

    int ed[16], es[16];
    #pragma unroll
    for (int j = 0; j < 16; ++j) {
        int e = e0 + j * 256 + t;
        if (e < NE) {
            ed[j] = dst[e];
            es[j] = src[e];
            atomicAdd(&hist[ed[j] >> 10], 1);
        } else ed[j] = -1;
    }
    __syncthreads();

    // parallel exclusive scan of hist over 128 threads
    if (t < 128) sc[t] = (t < SBUK) ? hist[t] : 0;
    __syncthreads();
    for (int off = 1; off < 128; off <<= 1) {
        int add = (t < 128 && t >= off) ? sc[t - off] : 0;
        __syncthreads();
        if (t < 128) sc[t] += add;
        __syncthreads();
    }
    if (t < SBUK) {
        lofs[t] = sc[t] - hist[t];
        base[t] = atomicAdd(&bcur[t], hist[t]);   // reserve global run
        hist[t] = lofs[t];                        // becomes lds cursor
    }
    __syncthreads();

    // order edges in LDS by bucket; record global position per element
    #pragma unroll
    for (int j = 0; j < 16; ++j) {
        if (ed[j] >= 0) {
            int b = ed[j] >> 10;
            int p = atomicAdd(&hist[b], 1);
            stageVal[p] = es[j] | ((ed[j] & 1023) << 17);
            stageGp[p]  = base[b] + (p - lofs[b]);
        }
    }
    __syncthreads();

    // writeout: consecutive lds idx -> consecutive global within each run
    for (int i = t; i < total; i += 256)
        pairs[stageGp[i]] = stageVal[i];
}

// ---------------------------------------------------------------------------
// Radix fill C: one block per 1024-node bucket; LDS node cursors; all esrc
// writes land in this block's ~65KB window (single-CU line ownership).
__global__ __launch_bounds__(1024) void partC_kernel(
    const int* __restrict__ offs, const int* __restrict__ pairs,
    int* __restrict__ esrc)
{
    __shared__ int lcur[1024];
    const int b  = blockIdx.x;
    const int t  = threadIdx.x;
    const int n0 = b << 10;
    int n = n0 + t;
    lcur[t] = (n < NN) ? offs[n] : 0;
    __syncthreads();
    const int start = offs[n0];
    const int end   = offs[min(n0 + 1024, NN)];
    for (int i = start + t; i < end; i += 1024) {
        int p   = pairs[i];
        int pos = atomicAdd(&lcur[((unsigned int)p) >> 17], 1);
        esrc[pos] = p & 0x1FFFF;
    }
}

// ---------------------------------------------------------------------------
__global__ __launch_bounds__(256) void convert_w_kernel(
    const float* __restrict__ w0, const float* __restrict__ w1,
    const float* __restrict__ w2, const float* __restrict__ w3,
    short* __restrict__ wt)
{
    const float* wsrc = (blockIdx.x == 0) ? w0 : (blockIdx.x == 1) ? w1
                      : (blockIdx.x == 2) ? w2 : w3;
    short* o = wt + blockIdx.x * 16384;
    for (int p = 0; p < 64; ++p) {
        int idx = p * 256 + threadIdx.x;
        int n = idx >> 7, k = idx & 127;
        o[n * 128 + k] = f2bf(wsrc[k * 128 + n]);
    }
}

// ---------------------------------------------------------------------------
// Gather + combine (bf16 in/out)
__global__ __launch_bounds__(256) void gather_kernel(
    const unsigned int* __restrict__ Xb, const int* __restrict__ offs,
    const int* __restrict__ esrc, const float* __restrict__ epsp,
    unsigned int* __restrict__ Ab)
{
    const int gid  = blockIdx.x * 256 + threadIdx.x;
    const int n    = gid >> 6;
    const int lane = threadIdx.x & 63;
    if (n >= NN) return;

    const int beg = offs[n], end = offs[n + 1];
    const float ep = 1.0f + epsp[0];

    float s0x = 0.f, s0y = 0.f, s1x = 0.f, s1y = 0.f;
    float s2x = 0.f, s2y = 0.f, s3x = 0.f, s3y = 0.f;
    union { unsigned int u; float f; } c;
    int i = beg;
    for (; i + 3 < end; i += 4) {
        unsigned int v0 = Xb[(size_t)esrc[i]     * 64 + lane];
        unsigned int v1 = Xb[(size_t)esrc[i + 1] * 64 + lane];
        unsigned int v2 = Xb[(size_t)esrc[i + 2] * 64 + lane];
        unsigned int v3 = Xb[(size_t)esrc[i + 3] * 64 + lane];
        c.u = v0 << 16;          s0x += c.f;
        c.u = v0 & 0xFFFF0000u;  s0y += c.f;
        c.u = v1 << 16;          s1x += c.f;
        c.u = v1 & 0xFFFF0000u;  s1y += c.f;
        c.u = v2 << 16;          s2x += c.f;
        c.u = v2 & 0xFFFF0000u;  s2y += c.f;
        c.u = v3 << 16;          s3x += c.f;
        c.u = v3 & 0xFFFF0000u;  s3y += c.f;
    }
    for (; i < end; ++i) {
        unsigned int v = Xb[(size_t)esrc[i] * 64 + lane];
        c.u = v << 16;           s0x += c.f;
        c.u = v & 0xFFFF0000u;   s0y += c.f;
    }
    unsigned int xv = Xb[(size_t)n * 64 + lane];
    float xl, xh;
    c.u = xv << 16;          xl = c.f;
    c.u = xv & 0xFFFF0000u;  xh = c.f;
    float ox = fmaf(ep, xl, (s0x + s1x) + (s2x + s3x));
    float oy = fmaf(ep, xh, (s0y + s1y) + (s2y + s3y));
    unsigned int lo = (unsigned short)f2bf(ox);
    unsigned int hi = (unsigned short)f2bf(oy);
    Ab[(size_t)n * 64 + lane] = lo | (hi << 16);
}

// ---------------------------------------------------------------------------
// MFMA GEMM1: kb-outer / n-inner -> 8 independent MFMA chains per wave.
__global__ __launch_bounds__(256) void gemm_stats_mfma(
    const short* __restrict__ Ab, const short* __restrict__ Wt,
    const float* __restrict__ bias, short* __restrict__ Hb,
    float* __restrict__ partial)
{
    __shared__ short As[64 * LDAS];
    __shared__ float sred[256];
    const int tid  = threadIdx.x;
    const int row0 = blockIdx.x * 64;

    #pragma unroll
    for (int p = 0; p < 4; ++p) {
        int c  = p * 256 + tid;
        int r  = c >> 4, k8 = c & 15;
        int row = row0 + r;
        short8 v = {};
        if (row < NN) v = *(const short8*)(Ab + (size_t)row * 128 + k8 * 8);
        *(short8*)(&As[r * LDAS + k8 * 8]) = v;
    }
    sred[tid] = 0.f;
    __syncthreads();

    const int w  = tid >> 6;
    const int l  = tid & 63;
    const int cl = l & 15;
    const int koff = (l >> 4) * 8;
    const int arow = w * 16 + cl;

    short8 afr[4];
    #pragma unroll
    for (int kb = 0; kb < 4; ++kb)
        afr[kb] = *(const short8*)(&As[arow * LDAS + kb * 32 + koff]);

    f32x4 acc[8] = {};
    #pragma unroll
    for (int kb = 0; kb < 4; ++kb) {
        #pragma unroll
        for (int n = 0; n < 8; ++n) {
            short8 bfr = *(const short8*)(Wt + (size_t)(n * 16 + cl) * 128
                                          + kb * 32 + koff);
            acc[n] = __builtin_amdgcn_mfma_f32_16x16x32_bf16(afr[kb], bfr,
                                                             acc[n], 0, 0, 0);
        }
    }

    #pragma unroll
    for (int n = 0; n < 8; ++n) {
        const int col = n * 16 + cl;
        const float bcol = bias[col];
        float ps = 0.f, pq = 0.f;
        #pragma unroll
        for (int i = 0; i < 4; ++i) {
            int row = row0 + w * 16 + ((l >> 4) << 2) + i;
            if (row < NN) {
                float h = acc[n][i] + bcol;
                Hb[(size_t)row * 128 + col] = f2bf(h);
                ps += h; pq += h * h;
            }
        }
        ps += __shfl_xor(ps, 16); pq += __shfl_xor(pq, 16);
        ps += __shfl_xor(ps, 32); pq += __shfl_xor(pq, 32);
        if (l < 16) {
            atomicAdd(&sred[col], ps);
            atomicAdd(&sred[128 + col], pq);
        }
    }
    __syncthreads();
    partial[(size_t)blockIdx.x * 256 + tid] = sred[tid];
}

// ---------------------------------------------------------------------------
__global__ __launch_bounds__(1024) void reduce_stats_kernel(
    const float* __restrict__ partial, const float* __restrict__ g,
    const float* __restrict__ bt, float* __restrict__ stats)
{
    __shared__ float buf[4][256];
    const int t  = threadIdx.x;
    const int c  = t & 255;
    const int ch = t >> 8;
    const int per = (NB_X + 3) / 4;
    const int b0 = ch * per;
    const int b1 = min(b0 + per, NB_X);

    float s = 0.f;
    #pragma unroll 8
    for (int b = b0; b < b1; ++b) s += partial[(size_t)b * 256 + c];
    buf[ch][c] = s;
    __syncthreads();

    if (t < 256) buf[0][t] = buf[0][t] + buf[1][t] + buf[2][t] + buf[3][t];
    __syncthreads();

    if (t < 128) {
        const float invN = 1.0f / (float)NN;
        float mu  = buf[0][t] * invN;
        float var = buf[0][128 + t] * invN - mu * mu;
        float sc  = g[t] * rsqrtf(var + 1e-5f);
        stats[256 + t] = sc;
        stats[384 + t] = bt[t] - mu * sc;
    }
}

// ---------------------------------------------------------------------------
// MFMA GEMM2: kb-outer / n-inner. mode=1: bf16+relu to Yb; mode=0: f32 to Yf.
__global__ __launch_bounds__(256) void gemm_post_mfma(
    const short* __restrict__ Hb, const float* __restrict__ stats,
    const short* __restrict__ Wt, const float* __restrict__ bias,
    short* __restrict__ Yb, float* __restrict__ Yf, int mode)
{
    __shared__ short As[64 * LDAS];
    const int tid  = threadIdx.x;
    const int row0 = blockIdx.x * 64;

    #pragma unroll
    for (int p = 0; p < 4; ++p) {
        int c  = p * 256 + tid;
        int r  = c >> 4, k8 = c & 15;
        int row = row0 + r;
        short8 v = {};
        if (row < NN) {
            short8 hv = *(const short8*)(Hb + (size_t)row * 128 + k8 * 8);
            #pragma unroll
            for (int j = 0; j < 8; ++j) {
                int k = k8 * 8 + j;
                union { unsigned int u; float f; } cv;
                cv.u = ((unsigned int)(unsigned short)hv[j]) << 16;
                float f = fmaxf(fmaf(cv.f, stats[256 + k], stats[384 + k]), 0.f);
                v[j] = f2bf(f);
            }
        }
        *(short8*)(&As[r * LDAS + k8 * 8]) = v;
    }
    __syncthreads();

    const int w  = tid >> 6;
    const int l  = tid & 63;
    const int cl = l & 15;
    const int koff = (l >> 4) * 8;
    const int arow = w * 16 + cl;

    short8 afr[4];
    #pragma unroll
    for (int kb = 0; kb < 4; ++kb)
        afr[kb] = *(const short8*)(&As[arow * LDAS + kb * 32 + koff]);

    f32x4 acc[8] = {};
    #pragma unroll
    for (int kb = 0; kb < 4; ++kb) {
        #pragma unroll
        for (int n = 0; n < 8; ++n) {
            short8 bfr = *(const short8*)(Wt + (size_t)(n * 16 + cl) * 128
                                          + kb * 32 + koff);
            acc[n] = __builtin_amdgcn_mfma_f32_16x16x32_bf16(afr[kb], bfr,
                                                             acc[n], 0, 0, 0);
        }
    }

    #pragma unroll
    for (int n = 0; n < 8; ++n) {
        const int col = n * 16 + cl;
        const float bcol = bias[col];
        #pragma unroll
        for (int i = 0; i < 4; ++i) {
            int row = row0 + w * 16 + ((l >> 4) << 2) + i;
            if (row < NN) {
                float h = acc[n][i] + bcol;
                if (mode == 1) {
                    h = fmaxf(h, 0.f);
                    Yb[(size_t)row * 128 + col] = f2bf(h);
                } else {
                    Yf[(size_t)row * 128 + col] = h;
                }
            }
        }
    }
}

// ---------------------------------------------------------------------------
extern "C" void kernel_launch(void* const* d_in, const int* in_sizes, int n_in,
                              void* d_out, int out_size, void* d_ws, size_t ws_size,
                              hipStream_t stream)
{
    const float* x    = (const float*)d_in[0];
    const int*   src  = (const int*)  d_in[1];
    const int*   dst  = (const int*)  d_in[2];
    const float* eps1 = (const float*)d_in[3];
    const float* w1a  = (const float*)d_in[4];
    const float* b1a  = (const float*)d_in[5];
    const float* g1   = (const float*)d_in[6];
    const float* bt1  = (const float*)d_in[7];
    const float* w1b  = (const float*)d_in[8];
    const float* b1b  = (const float*)d_in[9];
    const float* eps2 = (const float*)d_in[10];
    const float* w2a  = (const float*)d_in[11];
    const float* b2a  = (const float*)d_in[12];
    const float* g2   = (const float*)d_in[13];
    const float* bt2  = (const float*)d_in[14];
    const float* w2b  = (const float*)d_in[15];
    const float* b2b  = (const float*)d_in[16];

    float* out = (float*)d_out;

    // workspace layout (16B-aligned by construction)
    short*        Ab      = (short*)d_ws;                     // NN*128 bf16
    short*        Hb      = Ab + (size_t)NN * 128;            // NN*128 bf16
    unsigned int* Xcur    = (unsigned int*)(Hb + (size_t)NN * 128); // NN*64
    float*        stats   = (float*)(Xcur + (size_t)NN * 64); // 512
    float*        partial = stats + 512;                      // NB_X*256
    int*          offs    = (int*)(partial + (size_t)NB_X * 256); // NN+4
    int*          degcur  = offs + (NN + 4);                  // NN
    int*          esrc    = degcur + NN;                      // NE
    int*          pairs   = esrc + NE;                        // NE
    int*          scanned = pairs + NE;                       // NSB*1024
    int*          bsum    = scanned + NSB * 1024;             // 100 (pad)
    int*          bbase   = bsum + 100;                       // 100 (pad)
    int*          bcur    = bbase + 100;                      // 100 (pad)
    short*        wt      = (short*)(bcur + 100);             // 4*16384 bf16

    const int edge_blocks   = NE / 256;                  // 6250
    const int gather_blocks = (NN * 64 + 255) / 256;     // 25000
    const int convx_blocks  = NN * 64 / 256;             // 25000

    // ---- one-time prep ----
    convert_w_kernel<<<4, 256, 0, stream>>>(w1a, w1b, w2a, w2b, wt);
    convert_x_kernel<<<convx_blocks, 256, 0, stream>>>(x, Xcur);
    hipMemsetAsync(degcur, 0, NN * sizeof(int), stream);
    count_kernel<<<edge_blocks, 256, 0, stream>>>(dst, degcur);
    scan1_kernel<<<NSB, 1024, 0, stream>>>(degcur, scanned, bsum);
    scan2_kernel<<<1, 128, 0, stream>>>(bsum, bbase, offs);
    scan3_kernel<<<NSB, 1024, 0, stream>>>(scanned, bbase, offs);
    init_bcur_kernel<<<1, 128, 0, stream>>>(offs, bcur);
    partB_kernel<<<NBLK_B, 256, 0, stream>>>(src, dst, bcur, pairs);
    partC_kernel<<<SBUK, 1024, 0, stream>>>(offs, pairs, esrc);

    // ---- Layer 1 (input Xcur = bf16(x)) ----
    gather_kernel<<<gather_blocks, 256, 0, stream>>>(Xcur, offs, esrc, eps1,
                                                     (unsigned int*)Ab);
    gemm_stats_mfma<<<NB_X, 256, 0, stream>>>(Ab, wt, b1a, Hb, partial);
    reduce_stats_kernel<<<1, 1024, 0, stream>>>(partial, g1, bt1, stats);
    gemm_post_mfma<<<NB_X, 256, 0, stream>>>(Hb, stats, wt + 16384, b1b,
                                             (short*)Xcur, nullptr, 1);

    // ---- Layer 2 (input Xcur = bf16(relu(gin1))) ----
    gather_kernel<<<gather_blocks, 256, 0, stream>>>(Xcur, offs, esrc, eps2,
                                                     (unsigned int*)Ab);
    gemm_stats_mfma<<<NB_X, 256, 0, stream>>>(Ab, wt + 32768, b2a, Hb, partial);
    reduce_stats_kernel<<<1, 1024, 0, stream>>>(partial, g2, bt2, stats);
    gemm_post_mfma<<<NB_X, 256, 0, stream>>>(Hb, stats, wt + 49152, b2b,
                                             nullptr, out, 0);
}

// Round 9
// 477.237 us; speedup vs baseline: 1.9587x; 1.2998x over previous
//
#include <hip/hip_runtime.h>
#include <hip/hip_bf16.h>

#define NN 100000
#define NE 1600000
#define HIDD 128
#define NBG 782     // ceil(NN / 128) gemm blocks
#define SBUK 98     // super-buckets (1024 nodes each)
#define EPB 4096    // edges per partB/count98 block
#define NBLK_B 391  // ceil(NE / EPB)
#define LDAS 136    // A-tile LDS row stride in bf16 (272 B -> 2-way, free)

typedef short short8 __attribute__((ext_vector_type(8)));
typedef float f32x4 __attribute__((ext_vector_type(4)));

__device__ inline short f2bf(float f) {
    union { float f; unsigned int u; } v; v.f = f;
    unsigned int u = v.u + 0x7FFF + ((v.u >> 16) & 1);   // RNE
    return (short)(u >> 16);
}

// ---------------------------------------------------------------------------
// Convert X f32 -> packed bf16 pairs
__global__ __launch_bounds__(256) void convert_x_kernel(
    const float* __restrict__ X, unsigned int* __restrict__ Xb)
{
    int i = blockIdx.x * 256 + threadIdx.x;          // < NN*64
    const float2 v = *(const float2*)(X + (size_t)i * 2);
    unsigned int lo = (unsigned short)f2bf(v.x);
    unsigned int hi = (unsigned short)f2bf(v.y);
    Xb[i] = lo | (hi << 16);
}

// ---------------------------------------------------------------------------
// Bucket histogram: per-block LDS hist over 98 super-buckets -> global adds
__global__ __launch_bounds__(256) void count98_kernel(
    const int* __restrict__ dst, int* __restrict__ gtot)
{
    __shared__ int hist[SBUK];
    const int t  = threadIdx.x;
    const int e0 = blockIdx.x * EPB;
    for (int i = t; i < SBUK; i += 256) hist[i] = 0;
    __syncthreads();
    #pragma unroll
    for (int j = 0; j < 16; ++j) {
        int e = e0 + j * 256 + t;
        if (e < NE) atomicAdd(&hist[dst[e] >> 10], 1);
    }
    __syncthreads();
    for (int i = t; i < SBUK; i += 256)
        if (hist[i]) atomicAdd(&gtot[i], hist[i]);
}

// ---------------------------------------------------------------------------
// Scan 98 bucket totals -> bucket bases (bbase98[0..98]), init bcur, offs[NN]
__global__ __launch_bounds__(128) void scan98_kernel(
    const int* __restrict__ gtot, int* __restrict__ bbase98,
    int* __restrict__ bcur, int* __restrict__ offs)
{
    __shared__ int sh[128];
    const int t = threadIdx.x;
    int v = (t < SBUK) ? gtot[t] : 0;
    sh[t] = v;
    __syncthreads();
    for (int off = 1; off < 128; off <<= 1) {
        int add = (t >= off) ? sh[t - off] : 0;
        __syncthreads();
        sh[t] += add;
        __syncthreads();
    }
    if (t < SBUK) {
        int excl = sh[t] - v;
        bbase98[t] = excl;
        bcur[t]    = excl;
    }
    if (t == SBUK - 1) {
        bbase98[SBUK] = sh[t];   // == NE
        offs[NN]      = sh[t];
    }
}

// ---------------------------------------------------------------------------
// Radix fill B (staged, coalesced): LDS histogram + run reservation + ordered
// writeout of (src | dstLocal<<17) into bucket regions.
__global__ __launch_bounds__(256) void partB_kernel(
    const int* __restrict__ src, const int* __restrict__ dst,
    int* __restrict__ bcur, int* __restrict__ pairs)
{
    __shared__ int hist[SBUK];
    __shared__ int lofs[SBUK];
    __shared__ int base[SBUK];
    __shared__ int sc[128];
    __shared__ int stageVal[EPB];
    __shared__ int stageGp[EPB];
    const int t  = threadIdx.x;
    const int e0 = blockIdx.x * EPB;
    const int total = min(NE - e0, EPB);

    for (int i = t; i < SBUK; i += 256) hist[i] = 0;
    __syncthreads();

    int ed[16], es[16];
    #pragma unroll
    for (int j = 0; j < 16; ++j) {
        int e = e0 + j * 256 + t;
        if (e < NE) {
            ed[j] = dst[e];
            es[j] = src[e];
            atomicAdd(&hist[ed[j] >> 10], 1);
        } else ed[j] = -1;
    }
    __syncthreads();

    if (t < 128) sc[t] = (t < SBUK) ? hist[t] : 0;
    __syncthreads();
    for (int off = 1; off < 128; off <<= 1) {
        int add = (t < 128 && t >= off) ? sc[t - off] : 0;
        __syncthreads();
        if (t < 128) sc[t] += add;
        __syncthreads();
    }
    if (t < SBUK) {
        lofs[t] = sc[t] - hist[t];
        base[t] = atomicAdd(&bcur[t], hist[t]);
        hist[t] = lofs[t];
    }
    __syncthreads();

    #pragma unroll
    for (int j = 0; j < 16; ++j) {
        if (ed[j] >= 0) {
            int b = ed[j] >> 10;
            int p = atomicAdd(&hist[b], 1);
            stageVal[p] = es[j] | ((ed[j] & 1023) << 17);
            stageGp[p]  = base[b] + (p - lofs[b]);
        }
    }
    __syncthreads();

    for (int i = t; i < total; i += 256)
        pairs[stageGp[i]] = stageVal[i];
}

// ---------------------------------------------------------------------------
// partC counting-sort: one block per bucket; produces offs[] AND esrc[].
__global__ __launch_bounds__(1024) void partC_sort_kernel(
    const int* __restrict__ bbase98, const int* __restrict__ pairs,
    int* __restrict__ offs, int* __restrict__ esrc)
{
    __shared__ int cnt[1024];
    __shared__ int lcur[1024];
    __shared__ int wsum[16];
    const int b  = blockIdx.x;
    const int t  = threadIdx.x;
    const int n0 = b << 10;
    const int bstart = bbase98[b];
    const int bend   = bbase98[b + 1];

    cnt[t] = 0;
    __syncthreads();
    for (int i = bstart + t; i < bend; i += 1024)
        atomicAdd(&cnt[((unsigned int)pairs[i]) >> 17], 1);
    __syncthreads();

    // block-wide exclusive scan of cnt (shfl + wave sums)
    const int lane = t & 63;
    const int w    = t >> 6;
    int v = cnt[t];
    int x = v;
    #pragma unroll
    for (int off = 1; off < 64; off <<= 1) {
        int y = __shfl_up(x, off);
        if (lane >= off) x += y;
    }
    if (lane == 63) wsum[w] = x;
    __syncthreads();
    if (w == 0) {
        int s = (lane < 16) ? wsum[lane] : 0;
        #pragma unroll
        for (int off = 1; off < 16; off <<= 1) {
            int y = __shfl_up(s, off);
            if (lane >= off) s += y;
        }
        if (lane < 16) wsum[lane] = s;
    }
    __syncthreads();
    int excl = ((w > 0) ? wsum[w - 1] : 0) + x - v;
    int o = bstart + excl;
    int n = n0 + t;
    if (n < NN) offs[n] = o;
    lcur[t] = o;
    __syncthreads();

    for (int i = bstart + t; i < bend; i += 1024) {
        int p   = pairs[i];
        int pos = atomicAdd(&lcur[((unsigned int)p) >> 17], 1);
        esrc[pos] = p & 0x1FFFF;
    }
}

// ---------------------------------------------------------------------------
__global__ __launch_bounds__(256) void convert_w_kernel(
    const float* __restrict__ w0, const float* __restrict__ w1,
    const float* __restrict__ w2, const float* __restrict__ w3,
    short* __restrict__ wt)
{
    const float* wsrc = (blockIdx.x == 0) ? w0 : (blockIdx.x == 1) ? w1
                      : (blockIdx.x == 2) ? w2 : w3;
    short* o = wt + blockIdx.x * 16384;
    for (int p = 0; p < 64; ++p) {
        int idx = p * 256 + threadIdx.x;
        int n = idx >> 7, k = idx & 127;
        o[n * 128 + k] = f2bf(wsrc[k * 128 + n]);
    }
}

// ---------------------------------------------------------------------------
// Gather + combine (bf16 in/out): A[n] = bf16((1+eps)*X[n] + sum X[src(e)])
__global__ __launch_bounds__(256) void gather_kernel(
    const unsigned int* __restrict__ Xb, const int* __restrict__ offs,
    const int* __restrict__ esrc, const float* __restrict__ epsp,
    unsigned int* __restrict__ Ab)
{
    const int gid  = blockIdx.x * 256 + threadIdx.x;
    const int n    = gid >> 6;
    const int lane = threadIdx.x & 63;
    if (n >= NN) return;

    const int beg = offs[n], end = offs[n + 1];
    const float ep = 1.0f + epsp[0];

    float s0x = 0.f, s0y = 0.f, s1x = 0.f, s1y = 0.f;
    float s2x = 0.f, s2y = 0.f, s3x = 0.f, s3y = 0.f;
    union { unsigned int u; float f; } c;
    int i = beg;
    for (; i + 3 < end; i += 4) {
        unsigned int v0 = Xb[(size_t)esrc[i]     * 64 + lane];
        unsigned int v1 = Xb[(size_t)esrc[i + 1] * 64 + lane];
        unsigned int v2 = Xb[(size_t)esrc[i + 2] * 64 + lane];
        unsigned int v3 = Xb[(size_t)esrc[i + 3] * 64 + lane];
        c.u = v0 << 16;          s0x += c.f;
        c.u = v0 & 0xFFFF0000u;  s0y += c.f;
        c.u = v1 << 16;          s1x += c.f;
        c.u = v1 & 0xFFFF0000u;  s1y += c.f;
        c.u = v2 << 16;          s2x += c.f;
        c.u = v2 & 0xFFFF0000u;  s2y += c.f;
        c.u = v3 << 16;          s3x += c.f;
        c.u = v3 & 0xFFFF0000u;  s3y += c.f;
    }
    for (; i < end; ++i) {
        unsigned int v = Xb[(size_t)esrc[i] * 64 + lane];
        c.u = v << 16;           s0x += c.f;
        c.u = v & 0xFFFF0000u;   s0y += c.f;
    }
    unsigned int xv = Xb[(size_t)n * 64 + lane];
    float xl, xh;
    c.u = xv << 16;          xl = c.f;
    c.u = xv & 0xFFFF0000u;  xh = c.f;
    float ox = fmaf(ep, xl, (s0x + s1x) + (s2x + s3x));
    float oy = fmaf(ep, xh, (s0y + s1y) + (s2y + s3y));
    unsigned int lo = (unsigned short)f2bf(ox);
    unsigned int hi = (unsigned short)f2bf(oy);
    Ab[(size_t)n * 64 + lane] = lo | (hi << 16);
}

// ---------------------------------------------------------------------------
// MFMA GEMM1, BM=128: wave owns 32 rows (2 row-groups), B-frag reused x2.
__global__ __launch_bounds__(256) void gemm_stats_mfma(
    const short* __restrict__ Ab, const short* __restrict__ Wt,
    const float* __restrict__ bias, short* __restrict__ Hb,
    float* __restrict__ partial)
{
    __shared__ short As[128 * LDAS];
    __shared__ float sred[256];
    const int tid  = threadIdx.x;
    const int row0 = blockIdx.x * 128;

    #pragma unroll
    for (int p = 0; p < 8; ++p) {
        int c  = p * 256 + tid;
        int r  = c >> 4, k8 = c & 15;
        int row = row0 + r;
        short8 v = {};
        if (row < NN) v = *(const short8*)(Ab + (size_t)row * 128 + k8 * 8);
        *(short8*)(&As[r * LDAS + k8 * 8]) = v;
    }
    sred[tid] = 0.f;
    __syncthreads();

    const int w  = tid >> 6;
    const int l  = tid & 63;
    const int cl = l & 15;
    const int koff = (l >> 4) * 8;
    const int ar0 = w * 32 + cl;
    const int ar1 = w * 32 + 16 + cl;

    short8 a0f[4], a1f[4];
    #pragma unroll
    for (int kb = 0; kb < 4; ++kb) {
        a0f[kb] = *(const short8*)(&As[ar0 * LDAS + kb * 32 + koff]);
        a1f[kb] = *(const short8*)(&As[ar1 * LDAS + kb * 32 + koff]);
    }

    #pragma unroll
    for (int n = 0; n < 8; ++n) {
        short8 bfr[4];
        #pragma unroll
        for (int kb = 0; kb < 4; ++kb)
            bfr[kb] = *(const short8*)(Wt + (size_t)(n * 16 + cl) * 128
                                       + kb * 32 + koff);
        f32x4 acc0 = {0.f, 0.f, 0.f, 0.f};
        f32x4 acc1 = {0.f, 0.f, 0.f, 0.f};
        #pragma unroll
        for (int kb = 0; kb < 4; ++kb) {
            acc0 = __builtin_amdgcn_mfma_f32_16x16x32_bf16(a0f[kb], bfr[kb], acc0, 0, 0, 0);
            acc1 = __builtin_amdgcn_mfma_f32_16x16x32_bf16(a1f[kb], bfr[kb], acc1, 0, 0, 0);
        }
        const int col = n * 16 + cl;
        const float bcol = bias[col];
        float ps = 0.f, pq = 0.f;
        #pragma unroll
        for (int i = 0; i < 4; ++i) {
            int row = row0 + w * 32 + ((l >> 4) << 2) + i;
            if (row < NN) {
                float h = acc0[i] + bcol;
                Hb[(size_t)row * 128 + col] = f2bf(h);
                ps += h; pq += h * h;
            }
        }
        #pragma unroll
        for (int i = 0; i < 4; ++i) {
            int row = row0 + w * 32 + 16 + ((l >> 4) << 2) + i;
            if (row < NN) {
                float h = acc1[i] + bcol;
                Hb[(size_t)row * 128 + col] = f2bf(h);
                ps += h; pq += h * h;
            }
        }
        ps += __shfl_xor(ps, 16); pq += __shfl_xor(pq, 16);
        ps += __shfl_xor(ps, 32); pq += __shfl_xor(pq, 32);
        if (l < 16) {
            atomicAdd(&sred[col], ps);
            atomicAdd(&sred[128 + col], pq);
        }
    }
    __syncthreads();
    partial[(size_t)blockIdx.x * 256 + tid] = sred[tid];
}

// ---------------------------------------------------------------------------
__global__ __launch_bounds__(1024) void reduce_stats_kernel(
    const float* __restrict__ partial, const float* __restrict__ g,
    const float* __restrict__ bt, float* __restrict__ stats)
{
    __shared__ float buf[4][256];
    const int t  = threadIdx.x;
    const int c  = t & 255;
    const int ch = t >> 8;
    const int per = (NBG + 3) / 4;
    const int b0 = ch * per;
    const int b1 = min(b0 + per, NBG);

    float s = 0.f;
    #pragma unroll 8
    for (int b = b0; b < b1; ++b) s += partial[(size_t)b * 256 + c];
    buf[ch][c] = s;
    __syncthreads();

    if (t < 256) buf[0][t] = buf[0][t] + buf[1][t] + buf[2][t] + buf[3][t];
    __syncthreads();

    if (t < 128) {
        const float invN = 1.0f / (float)NN;
        float mu  = buf[0][t] * invN;
        float var = buf[0][128 + t] * invN - mu * mu;
        float sc  = g[t] * rsqrtf(var + 1e-5f);
        stats[256 + t] = sc;
        stats[384 + t] = bt[t] - mu * sc;
    }
}

// ---------------------------------------------------------------------------
// MFMA GEMM2, BM=128. mode=1: bf16+relu to Yb; mode=0: f32 to Yf.
__global__ __launch_bounds__(256) void gemm_post_mfma(
    const short* __restrict__ Hb, const float* __restrict__ stats,
    const short* __restrict__ Wt, const float* __restrict__ bias,
    short* __restrict__ Yb, float* __restrict__ Yf, int mode)
{
    __shared__ short As[128 * LDAS];
    const int tid  = threadIdx.x;
    const int row0 = blockIdx.x * 128;

    #pragma unroll
    for (int p = 0; p < 8; ++p) {
        int c  = p * 256 + tid;
        int r  = c >> 4, k8 = c & 15;
        int row = row0 + r;
        short8 v = {};
        if (row < NN) {
            short8 hv = *(const short8*)(Hb + (size_t)row * 128 + k8 * 8);
            #pragma unroll
            for (int j = 0; j < 8; ++j) {
                int k = k8 * 8 + j;
                union { unsigned int u; float f; } cv;
                cv.u = ((unsigned int)(unsigned short)hv[j]) << 16;
                float f = fmaxf(fmaf(cv.f, stats[256 + k], stats[384 + k]), 0.f);
                v[j] = f2bf(f);
            }
        }
        *(short8*)(&As[r * LDAS + k8 * 8]) = v;
    }
    __syncthreads();

    const int w  = tid >> 6;
    const int l  = tid & 63;
    const int cl = l & 15;
    const int koff = (l >> 4) * 8;
    const int ar0 = w * 32 + cl;
    const int ar1 = w * 32 + 16 + cl;

    short8 a0f[4], a1f[4];
    #pragma unroll
    for (int kb = 0; kb < 4; ++kb) {
        a0f[kb] = *(const short8*)(&As[ar0 * LDAS + kb * 32 + koff]);
        a1f[kb] = *(const short8*)(&As[ar1 * LDAS + kb * 32 + koff]);
    }

    #pragma unroll
    for (int n = 0; n < 8; ++n) {
        short8 bfr[4];
        #pragma unroll
        for (int kb = 0; kb < 4; ++kb)
            bfr[kb] = *(const short8*)(Wt + (size_t)(n * 16 + cl) * 128
                                       + kb * 32 + koff);
        f32x4 acc0 = {0.f, 0.f, 0.f, 0.f};
        f32x4 acc1 = {0.f, 0.f, 0.f, 0.f};
        #pragma unroll
        for (int kb = 0; kb < 4; ++kb) {
            acc0 = __builtin_amdgcn_mfma_f32_16x16x32_bf16(a0f[kb], bfr[kb], acc0, 0, 0, 0);
            acc1 = __builtin_amdgcn_mfma_f32_16x16x32_bf16(a1f[kb], bfr[kb], acc1, 0, 0, 0);
        }
        const int col = n * 16 + cl;
        const float bcol = bias[col];
        #pragma unroll
        for (int i = 0; i < 4; ++i) {
            int row = row0 + w * 32 + ((l >> 4) << 2) + i;
            if (row < NN) {
                float h = acc0[i] + bcol;
                if (mode == 1) { h = fmaxf(h, 0.f); Yb[(size_t)row * 128 + col] = f2bf(h); }
                else           { Yf[(size_t)row * 128 + col] = h; }
            }
        }
        #pragma unroll
        for (int i = 0; i < 4; ++i) {
            int row = row0 + w * 32 + 16 + ((l >> 4) << 2) + i;
            if (row < NN) {
                float h = acc1[i] + bcol;
                if (mode == 1) { h = fmaxf(h, 0.f); Yb[(size_t)row * 128 + col] = f2bf(h); }
                else           { Yf[(size_t)row * 128 + col] = h; }
            }
        }
    }
}

// ---------------------------------------------------------------------------
extern "C" void kernel_launch(void* const* d_in, const int* in_sizes, int n_in,
                              void* d_out, int out_size, void* d_ws, size_t ws_size,
                              hipStream_t stream)
{
    const float* x    = (const float*)d_in[0];
    const int*   src  = (const int*)  d_in[1];
    const int*   dst  = (const int*)  d_in[2];
    const float* eps1 = (const float*)d_in[3];
    const float* w1a  = (const float*)d_in[4];
    const float* b1a  = (const float*)d_in[5];
    const float* g1   = (const float*)d_in[6];
    const float* bt1  = (const float*)d_in[7];
    const float* w1b  = (const float*)d_in[8];
    const float* b1b  = (const float*)d_in[9];
    const float* eps2 = (const float*)d_in[10];
    const float* w2a  = (const float*)d_in[11];
    const float* b2a  = (const float*)d_in[12];
    const float* g2   = (const float*)d_in[13];
    const float* bt2  = (const float*)d_in[14];
    const float* w2b  = (const float*)d_in[15];
    const float* b2b  = (const float*)d_in[16];

    float* out = (float*)d_out;

    // workspace layout (16B-aligned by construction)
    short*        Ab      = (short*)d_ws;                     // NN*128 bf16
    short*        Hb      = Ab + (size_t)NN * 128;            // NN*128 bf16
    unsigned int* Xcur    = (unsigned int*)(Hb + (size_t)NN * 128); // NN*64
    float*        stats   = (float*)(Xcur + (size_t)NN * 64); // 512
    float*        partial = stats + 512;                      // NBG*256
    int*          offs    = (int*)(partial + (size_t)NBG * 256); // NN+4
    int*          esrc    = offs + (NN + 4);                  // NE
    int*          pairs   = esrc + NE;                        // NE
    int*          gtot    = pairs + NE;                       // 100 (pad)
    int*          bbase98 = gtot + 100;                       // 100 (pad)
    int*          bcur    = bbase98 + 100;                    // 100 (pad)
    short*        wt      = (short*)(bcur + 100);             // 4*16384 bf16

    const int gather_blocks = (NN * 64 + 255) / 256;     // 25000
    const int convx_blocks  = NN * 64 / 256;             // 25000

    // ---- one-time prep ----
    convert_w_kernel<<<4, 256, 0, stream>>>(w1a, w1b, w2a, w2b, wt);
    convert_x_kernel<<<convx_blocks, 256, 0, stream>>>(x, Xcur);
    hipMemsetAsync(gtot, 0, SBUK * sizeof(int), stream);
    count98_kernel<<<NBLK_B, 256, 0, stream>>>(dst, gtot);
    scan98_kernel<<<1, 128, 0, stream>>>(gtot, bbase98, bcur, offs);
    partB_kernel<<<NBLK_B, 256, 0, stream>>>(src, dst, bcur, pairs);
    partC_sort_kernel<<<SBUK, 1024, 0, stream>>>(bbase98, pairs, offs, esrc);

    // ---- Layer 1 (input Xcur = bf16(x)) ----
    gather_kernel<<<gather_blocks, 256, 0, stream>>>(Xcur, offs, esrc, eps1,
                                                     (unsigned int*)Ab);
    gemm_stats_mfma<<<NBG, 256, 0, stream>>>(Ab, wt, b1a, Hb, partial);
    reduce_stats_kernel<<<1, 1024, 0, stream>>>(partial, g1, bt1, stats);
    gemm_post_mfma<<<NBG, 256, 0, stream>>>(Hb, stats, wt + 16384, b1b,
                                            (short*)Xcur, nullptr, 1);

    // ---- Layer 2 (input Xcur = bf16(relu(gin1))) ----
    gather_kernel<<<gather_blocks, 256, 0, stream>>>(Xcur, offs, esrc, eps2,
                                                     (unsigned int*)Ab);
    gemm_stats_mfma<<<NBG, 256, 0, stream>>>(Ab, wt + 32768, b2a, Hb, partial);
    reduce_stats_kernel<<<1, 1024, 0, stream>>>(partial, g2, bt2, stats);
    gemm_post_mfma<<<NBG, 256, 0, stream>>>(Hb, stats, wt + 49152, b2b,
                                            nullptr, out, 0);
}